// Round 1
// baseline (374.227 us; speedup 1.0000x reference)
//
#include <hip/hip_runtime.h>

#define HEADS 4
#define OUT_CH 32
#define HC 128      // HEADS*OUT_CH
#define INC 128     // IN_CH
#define CAP 48      // per-row edge slot capacity (Poisson(16) tail safe)

typedef __attribute__((ext_vector_type(8))) short bfrag;   // 8 bf16
typedef __attribute__((ext_vector_type(4))) float ffrag;   // 4 fp32 acc

union U16 { uint4 u; bfrag f; };

__device__ __forceinline__ unsigned short f2bf(float f) {
  unsigned int u = __float_as_uint(f);
  unsigned int r = (u + 0x7FFFu + ((u >> 16) & 1u)) >> 16;
  return (unsigned short)r;
}

// ---------------------------------------------------------------------------
// prep: Wb = bf16(W) (16384 elems) and ce[h] = sum_c lew[h,c]*att_e[h,c]
__global__ void prep_kernel(const float* __restrict__ W,
                            const float* __restrict__ lew,
                            const float* __restrict__ att,
                            unsigned short* __restrict__ Wb,
                            float* __restrict__ ce) {
  int tid = threadIdx.x;
#pragma unroll
  for (int t = 0; t < 64; t++) {
    int idx = tid + t * 256;
    Wb[idx] = f2bf(W[idx]);
  }
  if (tid < HEADS) {
    float s = 0.f;
    for (int c = 0; c < OUT_CH; ++c)
      s += lew[tid * OUT_CH + c] * att[tid * 96 + 2 * OUT_CH + c];
    ce[tid] = s;
  }
}

// ---------------------------------------------------------------------------
// Fused: blocks [0,B) = edge-table atomic-append build (launched FIRST: it's
// the long pole); blocks [B,B+G) = MFMA GEMM (xh = x@W^T, bf16 out, + si/sj
// epilogue). GEMM is wave-synchronous (private LDS strip per wave, NO
// barriers) so the build branch's early return is safe.
// Build slot stores are NON-TEMPORAL: random 4B stores must not allocate
// dirty 64B lines in 8 non-shared XCD L2s (that partial-line writeback storm
// was the 124 MB WRITE_SIZE); let the 256MB Infinity Cache merge them.
#define APITCH 136  // ushort pitch for 128-k row: ds_read_b128 <=2-way free
__global__ __launch_bounds__(256) void gemm_build(
    const float* __restrict__ x, const unsigned short* __restrict__ Wb,
    const float* __restrict__ att, const int* __restrict__ ei,
    const float* __restrict__ ea, unsigned short* __restrict__ xhb,
    float* __restrict__ si, float* __restrict__ sj, int* __restrict__ cnt,
    unsigned int* __restrict__ slots, int nrows, int E, int B) {
  __shared__ unsigned short Als[4][16 * APITCH];  // 17408 B

  if (blockIdx.x < B) {
    // ---- edge-table build branch ----
    int e = blockIdx.x * 256 + threadIdx.x;
    if (e < E) {
      int r = ei[e];
      int c = ei[E + e];
      unsigned int u = __float_as_uint(ea[e]);
      unsigned int word = ((u + 0x10000u) & 0xFFFE0000u) | (unsigned int)c;
      int pos = atomicAdd(&cnt[r], 1);
      if (pos < CAP)
        __builtin_nontemporal_store(word, &slots[(size_t)r * CAP + pos]);
    }
    return;
  }

  // ---- MFMA GEMM branch: each wave owns 16 rows ----
  const int tid = threadIdx.x;
  const int wid = tid >> 6;
  const int lane = tid & 63;
  const int row0 = (blockIdx.x - B) * 64 + wid * 16;
  if (row0 >= nrows) return;
  unsigned short* As = &Als[wid][0];

  // stage 16 rows x 128 k: fp32 -> bf16 into private LDS strip (no barrier)
#pragma unroll
  for (int t = 0; t < 8; t++) {
    int idx = t * 64 + lane;        // 512 float4 total
    int r = idx >> 5;               // 32 float4 per row
    int q = idx & 31;
    int gr = row0 + r;
    float4 v = make_float4(0.f, 0.f, 0.f, 0.f);
    if (gr < nrows) v = ((const float4*)x)[(size_t)gr * 32 + q];
    unsigned int p0 = ((unsigned int)f2bf(v.y) << 16) | f2bf(v.x);
    unsigned int p1 = ((unsigned int)f2bf(v.w) << 16) | f2bf(v.z);
    *(uint2*)&As[r * APITCH + q * 4] = make_uint2(p0, p1);
  }

  const int m15 = lane & 15;
  const int g = lane >> 4;

  ffrag acc[8];
#pragma unroll
  for (int t = 0; t < 8; t++) acc[t] = (ffrag){0.f, 0.f, 0.f, 0.f};

#pragma unroll
  for (int ks = 0; ks < 4; ks++) {
    U16 a;
    a.u = *(const uint4*)&As[m15 * APITCH + ks * 32 + g * 8];
#pragma unroll
    for (int nt = 0; nt < 8; nt++) {
      U16 b;
      b.u = *(const uint4*)&Wb[(size_t)(nt * 16 + m15) * 128 + ks * 32 + g * 8];
      acc[nt] = __builtin_amdgcn_mfma_f32_16x16x32_bf16(a.f, b.f, acc[nt],
                                                        0, 0, 0);
    }
  }

  // ---- si/sj epilogue (C layout: col=lane&15 -> n, row=(lane>>4)*4+reg) ----
  float ai[8], aj[8];
#pragma unroll
  for (int t = 0; t < 8; t++) {
    int h = t >> 1, c = (t & 1) * 16 + m15;
    ai[t] = att[h * 96 + c];
    aj[t] = att[h * 96 + 32 + c];
  }
#pragma unroll
  for (int reg = 0; reg < 4; reg++) {
    float ph_i[4], ph_j[4];
#pragma unroll
    for (int h = 0; h < 4; h++) {
      ph_i[h] = acc[2 * h][reg] * ai[2 * h] + acc[2 * h + 1][reg] * ai[2 * h + 1];
      ph_j[h] = acc[2 * h][reg] * aj[2 * h] + acc[2 * h + 1][reg] * aj[2 * h + 1];
    }
#pragma unroll
    for (int off = 8; off >= 1; off >>= 1) {
#pragma unroll
      for (int h = 0; h < 4; h++) {
        ph_i[h] += __shfl_down(ph_i[h], off, 16);
        ph_j[h] += __shfl_down(ph_j[h], off, 16);
      }
    }
    int gr = row0 + g * 4 + reg;
    if (m15 == 0 && gr < nrows) {
#pragma unroll
      for (int h = 0; h < 4; h++) {
        si[(size_t)gr * 4 + h] = ph_i[h];
        sj[(size_t)gr * 4 + h] = ph_j[h];
      }
    }
  }

  // ---- bf16 repack via private LDS strip (pitch 128), coalesced store ----
#pragma unroll
  for (int t = 0; t < 8; t++) {
#pragma unroll
    for (int reg = 0; reg < 4; reg++) {
      int r = g * 4 + reg;
      int n = t * 16 + m15;
      As[r * 128 + n] = f2bf(acc[t][reg]);
    }
  }
  const uint4* src = (const uint4*)As;
#pragma unroll
  for (int t = 0; t < 4; t++) {
    int idx = t * 64 + lane;        // 256 uint4, 16 per row
    int r = idx >> 4, q = idx & 15;
    int gr = row0 + r;
    if (gr < nrows) ((uint4*)(xhb + (size_t)gr * 128))[q] = src[idx];
  }
}

// ---------------------------------------------------------------------------
// Gather, restructured for latency tolerance. One wave per destination node.
// Phase 1: lane i owns edge i (m <= CAP=48 <= 64): ONE slot load, ONE float4
//   sj gather (sj = 1.6 MB, L2-resident), 4 exps -> per-edge weights for all
//   4 heads. All lanes fully parallel: the old ww->sj->shuffle->xhb serial
//   chain is gone.
// Phase 2: per edge, broadcast (c, w[h]) by in-wave shuffles (register data,
//   no memory latency), then the only memory op in the loop is the coalesced
//   256B xhb row gather, issued 4-deep. Padding lanes carry (c=0, w=0) so
//   the 4-unrolled loop needs no tail.
__global__ __launch_bounds__(256) void gather_kernel(
    const int* __restrict__ cnt, const unsigned int* __restrict__ slots,
    const float* __restrict__ si, const float* __restrict__ sj,
    const float* __restrict__ ce, const unsigned short* __restrict__ xhb,
    float* __restrict__ out, int n) {
  int node = blockIdx.x * 4 + (threadIdx.x >> 6);
  if (node >= n) return;
  int lane = threadIdx.x & 63;
  int h = lane >> 4;

  int m = cnt[node];
  if (m > CAP) m = CAP;

  float4 si4 = *(const float4*)(si + (size_t)node * 4);
  float4 ce4 = *(const float4*)ce;

  // ---- phase 1: per-lane edge weights ----
  int c = 0;
  float w0 = 0.f, w1 = 0.f, w2 = 0.f, w3 = 0.f;
  if (lane < m) {
    unsigned int word = slots[(size_t)node * CAP + lane];
    c = word & 0x1FFFF;
    float eaf = __uint_as_float(word & 0xFFFE0000u);
    float4 sjv = *(const float4*)(sj + (size_t)c * 4);
    float t0 = si4.x + sjv.x + eaf * ce4.x;
    float t1 = si4.y + sjv.y + eaf * ce4.y;
    float t2 = si4.z + sjv.z + eaf * ce4.z;
    float t3 = si4.w + sjv.w + eaf * ce4.w;
    t0 = t0 > 0.f ? t0 : 0.2f * t0;
    t1 = t1 > 0.f ? t1 : 0.2f * t1;
    t2 = t2 > 0.f ? t2 : 0.2f * t2;
    t3 = t3 > 0.f ? t3 : 0.2f * t3;
    w0 = __expf(t0);
    w1 = __expf(t1);
    w2 = __expf(t2);
    w3 = __expf(t3);
  }

  // ---- phase 2: pipelined xhb row gathers ----
  const unsigned short* xb = xhb + lane * 2;  // lane -> channels 2l,2l+1
  float acc0 = 0.f, acc1 = 0.f, wsum = 0.f;
  for (int k = 0; k < m; k += 4) {
    int c0 = __shfl(c, k);
    int c1 = __shfl(c, k + 1);
    int c2 = __shfl(c, k + 2);
    int c3 = __shfl(c, k + 3);
    float a0 = __shfl(w0, k), a1 = __shfl(w1, k), a2 = __shfl(w2, k),
          a3 = __shfl(w3, k);
    float b0 = __shfl(w0, k + 1), b1 = __shfl(w1, k + 1),
          b2 = __shfl(w2, k + 1), b3 = __shfl(w3, k + 1);
    float d0 = __shfl(w0, k + 2), d1 = __shfl(w1, k + 2),
          d2 = __shfl(w2, k + 2), d3 = __shfl(w3, k + 2);
    float e0 = __shfl(w0, k + 3), e1 = __shfl(w1, k + 3),
          e2 = __shfl(w2, k + 3), e3 = __shfl(w3, k + 3);
    float wa = h == 0 ? a0 : (h == 1 ? a1 : (h == 2 ? a2 : a3));
    float wb = h == 0 ? b0 : (h == 1 ? b1 : (h == 2 ? b2 : b3));
    float wc = h == 0 ? d0 : (h == 1 ? d1 : (h == 2 ? d2 : d3));
    float wd = h == 0 ? e0 : (h == 1 ? e1 : (h == 2 ? e2 : e3));
    unsigned int x0 = *(const unsigned int*)(xb + (size_t)c0 * 128);
    unsigned int x1 = *(const unsigned int*)(xb + (size_t)c1 * 128);
    unsigned int x2 = *(const unsigned int*)(xb + (size_t)c2 * 128);
    unsigned int x3 = *(const unsigned int*)(xb + (size_t)c3 * 128);
    acc0 += wa * __uint_as_float(x0 << 16) + wb * __uint_as_float(x1 << 16) +
            wc * __uint_as_float(x2 << 16) + wd * __uint_as_float(x3 << 16);
    acc1 += wa * __uint_as_float(x0 & 0xFFFF0000u) +
            wb * __uint_as_float(x1 & 0xFFFF0000u) +
            wc * __uint_as_float(x2 & 0xFFFF0000u) +
            wd * __uint_as_float(x3 & 0xFFFF0000u);
    wsum += wa + wb + wc + wd;
  }

  float inv = 1.0f / (wsum + 1e-16f);
  union { float f[2]; unsigned long long u; } pk;
  pk.f[0] = acc0 * inv;
  pk.f[1] = acc1 * inv;
  // out is write-once streaming: keep it out of L2 (xhb/sj want the space)
  __builtin_nontemporal_store(
      pk.u, (unsigned long long*)(out + (size_t)node * HC + lane * 2));
}

// ---------------------------------------------------------------------------
extern "C" void kernel_launch(void* const* d_in, const int* in_sizes, int n_in,
                              void* d_out, int out_size, void* d_ws,
                              size_t ws_size, hipStream_t stream) {
  const float* x = (const float*)d_in[0];
  const float* edge_attr = (const float*)d_in[1];
  const int* ei = (const int*)d_in[2];
  const float* lin_w = (const float*)d_in[3];
  const float* lew = (const float*)d_in[4];
  const float* att = (const float*)d_in[5];
  float* out = (float*)d_out;

  const int N = in_sizes[0] / INC;
  const int E = in_sizes[1];

  // workspace layout (4-byte units; all segments 16 B aligned)
  unsigned int* slots = (unsigned int*)d_ws;                         // N*CAP
  unsigned short* xhb = (unsigned short*)(slots + (size_t)N * CAP);  // N*128
  float* si = (float*)(xhb + (size_t)N * 128);                       // N*4
  float* sj = si + (size_t)N * 4;                                    // N*4
  float* ce = sj + (size_t)N * 4;                                    // 16
  unsigned short* Wb = (unsigned short*)(ce + 16);                   // 16384
  int* cnt = (int*)(Wb + 16384);                                     // N

  hipMemsetAsync(cnt, 0, (size_t)N * sizeof(int), stream);
  prep_kernel<<<1, 256, 0, stream>>>(lin_w, lew, att, Wb, ce);

  const int G = (N + 63) / 64;       // gemm blocks (4 waves x 16 rows)
  const int B = (E + 255) / 256;     // build blocks (dispatched first)
  gemm_build<<<G + B, 256, 0, stream>>>(x, Wb, att, ei, edge_attr, xhb, si,
                                        sj, cnt, slots, N, E, B);
  gather_kernel<<<(N + 3) / 4, 256, 0, stream>>>(cnt, slots, si, sj, ce, xhb,
                                                 out, N);
}

// Round 2
// 298.193 us; speedup vs baseline: 1.2550x; 1.2550x over previous
//
#include <hip/hip_runtime.h>

#define HEADS 4
#define OUT_CH 32
#define HC 128      // HEADS*OUT_CH
#define INC 128     // IN_CH
#define CAP 48      // per-row edge slot capacity (Poisson(16) tail safe)

typedef __attribute__((ext_vector_type(8))) short bfrag;   // 8 bf16
typedef __attribute__((ext_vector_type(4))) float ffrag;   // 4 fp32 acc

union U16 { uint4 u; bfrag f; };

__device__ __forceinline__ unsigned short f2bf(float f) {
  unsigned int u = __float_as_uint(f);
  unsigned int r = (u + 0x7FFFu + ((u >> 16) & 1u)) >> 16;
  return (unsigned short)r;
}

// ---------------------------------------------------------------------------
// prep: Wb = bf16(W) (16384 elems) and ce[h] = sum_c lew[h,c]*att_e[h,c]
__global__ void prep_kernel(const float* __restrict__ W,
                            const float* __restrict__ lew,
                            const float* __restrict__ att,
                            unsigned short* __restrict__ Wb,
                            float* __restrict__ ce) {
  int tid = threadIdx.x;
#pragma unroll
  for (int t = 0; t < 64; t++) {
    int idx = tid + t * 256;
    Wb[idx] = f2bf(W[idx]);
  }
  if (tid < HEADS) {
    float s = 0.f;
    for (int c = 0; c < OUT_CH; ++c)
      s += lew[tid * OUT_CH + c] * att[tid * 96 + 2 * OUT_CH + c];
    ce[tid] = s;
  }
}

// ---------------------------------------------------------------------------
// Fused: blocks [0,G) = MFMA GEMM (xh = x@W^T, bf16 out, + si/sj epilogue);
// blocks [G,G+B) = edge-table atomic-append build.
// ROUND-0 PROVEN ORDERING: GEMM blocks first — the latency-bound build
// overlaps with GEMM compute on the same CUs (build-first cost +45 µs, R1).
// Plain slot store — nontemporal did NOT reduce the 124 MB writeback (R1).
#define APITCH 136  // ushort pitch for 128-k row: ds_read_b128 <=2-way free
__global__ __launch_bounds__(256) void gemm_build(
    const float* __restrict__ x, const unsigned short* __restrict__ Wb,
    const float* __restrict__ att, const int* __restrict__ ei,
    const float* __restrict__ ea, unsigned short* __restrict__ xhb,
    float* __restrict__ si, float* __restrict__ sj, int* __restrict__ cnt,
    unsigned int* __restrict__ slots, int nrows, int E, int G) {
  __shared__ unsigned short Als[4][16 * APITCH];  // 17408 B

  if (blockIdx.x >= G) {
    // ---- edge-table build branch ----
    int e = (blockIdx.x - G) * 256 + threadIdx.x;
    if (e < E) {
      int r = ei[e];
      int c = ei[E + e];
      unsigned int u = __float_as_uint(ea[e]);
      unsigned int word = ((u + 0x10000u) & 0xFFFE0000u) | (unsigned int)c;
      int pos = atomicAdd(&cnt[r], 1);
      if (pos < CAP) slots[(size_t)r * CAP + pos] = word;
    }
    return;
  }

  // ---- MFMA GEMM branch: each wave owns 16 rows ----
  const int tid = threadIdx.x;
  const int wid = tid >> 6;
  const int lane = tid & 63;
  const int row0 = blockIdx.x * 64 + wid * 16;
  if (row0 >= nrows) return;
  unsigned short* As = &Als[wid][0];

  // stage 16 rows x 128 k: fp32 -> bf16 into private LDS strip (no barrier)
#pragma unroll
  for (int t = 0; t < 8; t++) {
    int idx = t * 64 + lane;        // 512 float4 total
    int r = idx >> 5;               // 32 float4 per row
    int q = idx & 31;
    int gr = row0 + r;
    float4 v = make_float4(0.f, 0.f, 0.f, 0.f);
    if (gr < nrows) v = ((const float4*)x)[(size_t)gr * 32 + q];
    unsigned int p0 = ((unsigned int)f2bf(v.y) << 16) | f2bf(v.x);
    unsigned int p1 = ((unsigned int)f2bf(v.w) << 16) | f2bf(v.z);
    *(uint2*)&As[r * APITCH + q * 4] = make_uint2(p0, p1);
  }

  const int m15 = lane & 15;
  const int g = lane >> 4;

  ffrag acc[8];
#pragma unroll
  for (int t = 0; t < 8; t++) acc[t] = (ffrag){0.f, 0.f, 0.f, 0.f};

#pragma unroll
  for (int ks = 0; ks < 4; ks++) {
    U16 a;
    a.u = *(const uint4*)&As[m15 * APITCH + ks * 32 + g * 8];
#pragma unroll
    for (int nt = 0; nt < 8; nt++) {
      U16 b;
      b.u = *(const uint4*)&Wb[(size_t)(nt * 16 + m15) * 128 + ks * 32 + g * 8];
      acc[nt] = __builtin_amdgcn_mfma_f32_16x16x32_bf16(a.f, b.f, acc[nt],
                                                        0, 0, 0);
    }
  }

  // ---- si/sj epilogue (C layout: col=lane&15 -> n, row=(lane>>4)*4+reg) ----
  float ai[8], aj[8];
#pragma unroll
  for (int t = 0; t < 8; t++) {
    int h = t >> 1, c = (t & 1) * 16 + m15;
    ai[t] = att[h * 96 + c];
    aj[t] = att[h * 96 + 32 + c];
  }
#pragma unroll
  for (int reg = 0; reg < 4; reg++) {
    float ph_i[4], ph_j[4];
#pragma unroll
    for (int h = 0; h < 4; h++) {
      ph_i[h] = acc[2 * h][reg] * ai[2 * h] + acc[2 * h + 1][reg] * ai[2 * h + 1];
      ph_j[h] = acc[2 * h][reg] * aj[2 * h] + acc[2 * h + 1][reg] * aj[2 * h + 1];
    }
#pragma unroll
    for (int off = 8; off >= 1; off >>= 1) {
#pragma unroll
      for (int h = 0; h < 4; h++) {
        ph_i[h] += __shfl_down(ph_i[h], off, 16);
        ph_j[h] += __shfl_down(ph_j[h], off, 16);
      }
    }
    int gr = row0 + g * 4 + reg;
    if (m15 == 0 && gr < nrows) {
#pragma unroll
      for (int h = 0; h < 4; h++) {
        si[(size_t)gr * 4 + h] = ph_i[h];
        sj[(size_t)gr * 4 + h] = ph_j[h];
      }
    }
  }

  // ---- bf16 repack via private LDS strip (pitch 128), coalesced store ----
#pragma unroll
  for (int t = 0; t < 8; t++) {
#pragma unroll
    for (int reg = 0; reg < 4; reg++) {
      int r = g * 4 + reg;
      int n = t * 16 + m15;
      As[r * 128 + n] = f2bf(acc[t][reg]);
    }
  }
  const uint4* src = (const uint4*)As;
#pragma unroll
  for (int t = 0; t < 4; t++) {
    int idx = t * 64 + lane;        // 256 uint4, 16 per row
    int r = idx >> 4, q = idx & 15;
    int gr = row0 + r;
    if (gr < nrows) ((uint4*)(xhb + (size_t)gr * 128))[q] = src[idx];
  }
}

// ---------------------------------------------------------------------------
// Gather v2: one wave per destination node, two phases, LDS-broadcast.
// Phase 1 (parallel): lane i owns edge i (m <= CAP=48): ONE slot load, ONE
//   float4 sj gather, 4 exps -> weights for all 4 heads. All lanes
//   independent — full MLP on the sj gathers, no serial chain. Results go
//   to a PER-WAVE LDS strip: c[48] and head-transposed w[4][48] (so phase-2
//   reads are contiguous float4 per head). Padding lanes write c=0, w=0.
// Phase 2: per 4 edges only 2 LDS reads: int4 of columns (uniform address =
//   broadcast) + float4 of this head's weights (4 addrs, 2-way bank alias =
//   free). The xhb row gathers (coalesced 256 B/edge) depend only on LDS
//   data -> the compiler can issue many iterations of loads back-to-back.
//   R1's 20-shuffles-per-4-edges distribution is gone (that was the
//   regression); same-wave LDS dependency needs no barrier.
__global__ __launch_bounds__(256) void gather_kernel(
    const int* __restrict__ cnt, const unsigned int* __restrict__ slots,
    const float* __restrict__ si, const float* __restrict__ sj,
    const float* __restrict__ ce, const unsigned short* __restrict__ xhb,
    float* __restrict__ out, int n) {
  __shared__ int cls[4][CAP];        // per-wave column lists
  __shared__ float wls[4][4][CAP];   // per-wave [head][edge] weights

  int wid = threadIdx.x >> 6;
  int node = blockIdx.x * 4 + wid;
  if (node >= n) return;
  int lane = threadIdx.x & 63;
  int h = lane >> 4;

  int m = cnt[node];
  if (m > CAP) m = CAP;

  float4 si4 = *(const float4*)(si + (size_t)node * 4);
  float4 ce4 = *(const float4*)ce;

  // ---- phase 1: per-lane edge weights -> LDS ----
  if (lane < CAP) {
    int c = 0;
    float w0 = 0.f, w1 = 0.f, w2 = 0.f, w3 = 0.f;
    if (lane < m) {
      unsigned int word = slots[(size_t)node * CAP + lane];
      c = word & 0x1FFFF;
      float eaf = __uint_as_float(word & 0xFFFE0000u);
      float4 sjv = *(const float4*)(sj + (size_t)c * 4);
      float t0 = si4.x + sjv.x + eaf * ce4.x;
      float t1 = si4.y + sjv.y + eaf * ce4.y;
      float t2 = si4.z + sjv.z + eaf * ce4.z;
      float t3 = si4.w + sjv.w + eaf * ce4.w;
      t0 = t0 > 0.f ? t0 : 0.2f * t0;
      t1 = t1 > 0.f ? t1 : 0.2f * t1;
      t2 = t2 > 0.f ? t2 : 0.2f * t2;
      t3 = t3 > 0.f ? t3 : 0.2f * t3;
      w0 = __expf(t0);
      w1 = __expf(t1);
      w2 = __expf(t2);
      w3 = __expf(t3);
    }
    cls[wid][lane] = c;
    wls[wid][0][lane] = w0;
    wls[wid][1][lane] = w1;
    wls[wid][2][lane] = w2;
    wls[wid][3][lane] = w3;
  }
  // same-wave LDS dependency: compiler-inserted lgkmcnt orders write->read.

  // ---- phase 2: pipelined xhb row gathers ----
  const unsigned short* xb = xhb + lane * 2;  // lane -> channels 2l,2l+1
  float acc0 = 0.f, acc1 = 0.f, wsum = 0.f;
  for (int k = 0; k < m; k += 4) {
    int4 cc = *(const int4*)&cls[wid][k];
    float4 wv = *(const float4*)&wls[wid][h][k];
    unsigned int x0 = *(const unsigned int*)(xb + (size_t)cc.x * 128);
    unsigned int x1 = *(const unsigned int*)(xb + (size_t)cc.y * 128);
    unsigned int x2 = *(const unsigned int*)(xb + (size_t)cc.z * 128);
    unsigned int x3 = *(const unsigned int*)(xb + (size_t)cc.w * 128);
    acc0 += wv.x * __uint_as_float(x0 << 16) +
            wv.y * __uint_as_float(x1 << 16) +
            wv.z * __uint_as_float(x2 << 16) +
            wv.w * __uint_as_float(x3 << 16);
    acc1 += wv.x * __uint_as_float(x0 & 0xFFFF0000u) +
            wv.y * __uint_as_float(x1 & 0xFFFF0000u) +
            wv.z * __uint_as_float(x2 & 0xFFFF0000u) +
            wv.w * __uint_as_float(x3 & 0xFFFF0000u);
    wsum += wv.x + wv.y + wv.z + wv.w;
  }

  float inv = 1.0f / (wsum + 1e-16f);
  float2 o;
  o.x = acc0 * inv;
  o.y = acc1 * inv;
  *(float2*)(out + (size_t)node * HC + lane * 2) = o;
}

// ---------------------------------------------------------------------------
extern "C" void kernel_launch(void* const* d_in, const int* in_sizes, int n_in,
                              void* d_out, int out_size, void* d_ws,
                              size_t ws_size, hipStream_t stream) {
  const float* x = (const float*)d_in[0];
  const float* edge_attr = (const float*)d_in[1];
  const int* ei = (const int*)d_in[2];
  const float* lin_w = (const float*)d_in[3];
  const float* lew = (const float*)d_in[4];
  const float* att = (const float*)d_in[5];
  float* out = (float*)d_out;

  const int N = in_sizes[0] / INC;
  const int E = in_sizes[1];

  // workspace layout (4-byte units; all segments 16 B aligned)
  unsigned int* slots = (unsigned int*)d_ws;                         // N*CAP
  unsigned short* xhb = (unsigned short*)(slots + (size_t)N * CAP);  // N*128
  float* si = (float*)(xhb + (size_t)N * 128);                       // N*4
  float* sj = si + (size_t)N * 4;                                    // N*4
  float* ce = sj + (size_t)N * 4;                                    // 16
  unsigned short* Wb = (unsigned short*)(ce + 16);                   // 16384
  int* cnt = (int*)(Wb + 16384);                                     // N

  hipMemsetAsync(cnt, 0, (size_t)N * sizeof(int), stream);
  prep_kernel<<<1, 256, 0, stream>>>(lin_w, lew, att, Wb, ce);

  const int G = (N + 63) / 64;       // gemm blocks (4 waves x 16 rows)
  const int B = (E + 255) / 256;     // build blocks
  gemm_build<<<G + B, 256, 0, stream>>>(x, Wb, att, ei, edge_attr, xhb, si,
                                        sj, cnt, slots, N, E, G);
  gather_kernel<<<(N + 3) / 4, 256, 0, stream>>>(cnt, slots, si, sj, ce, xhb,
                                                 out, N);
}